// Round 2
// baseline (5863.724 us; speedup 1.0000x reference)
//
#include <hip/hip_runtime.h>
#include <math.h>

// CGConv: N=100000 atoms, M=12 nbrs, F=64 atom-feat, B=41 bond-feat
// gated = [self | nbr | bond] @ W + b ; BN1 over N*M rows ;
// summed = sum_j sigmoid(filter)*softplus(core) ; BN2 over N rows ;
// out = softplus(atom + summed_bn)
//
// W rows split: W_self(64x128), W_nbr(64x128), W_bond(41x128).
// Pself = atom@W_self, Pnbr = atom@W_nbr precomputed per-atom (k_project).
// Per-pair work is only the K=41 bond dot, done twice (stats pass + main
// pass) because BN1 batch stats must precede the nonlinearity.
//
// R1: occupancy fix. Stats pass = 1 channel/thread (41 W regs,
// launch_bounds(256,6) -> <=85 VGPR). Main pass keeps channel pairs
// (f, f+64) but capped at 128 VGPR with unroll-4 gather pipeline.

#define NATOMS  100000
#define MNBR    12
#define FDIM    64
#define BDIM    41
#define C2F     128
#define BONDROW (MNBR*BDIM)   // 492
#define EPSBN   1e-5f
#define NBLK    2048          // grid for pair kernels (= #partial slots)

__device__ __forceinline__ float softplusf(float x) {
    return fmaxf(x, 0.f) + log1pf(__expf(-fabsf(x)));
}
__device__ __forceinline__ float sigmoidf(float x) {
    return 1.f / (1.f + __expf(-x));
}

// ---------------- kernel 1: per-atom projections ----------------
__global__ __launch_bounds__(256) void k_project(
    const float* __restrict__ atom, const float* __restrict__ W,
    float* __restrict__ Pself, float* __restrict__ Pnbr)
{
    __shared__ float Arow[8][64];
    const int tid  = threadIdx.x;
    const int c    = tid & 127;
    const int half = tid >> 7;           // 0 -> Pself, 1 -> Pnbr
    float w[64];
    #pragma unroll
    for (int k = 0; k < 64; ++k)
        w[k] = W[(half*64 + k)*C2F + c];
    float* Pout = half ? Pnbr : Pself;

    for (int i0 = blockIdx.x*8; i0 < NATOMS; i0 += gridDim.x*8) {
        __syncthreads();
        for (int idx = tid; idx < 8*64; idx += 256) {
            int a = idx >> 6, k = idx & 63, i = i0 + a;
            Arow[a][k] = (i < NATOMS) ? atom[i*FDIM + k] : 0.f;
        }
        __syncthreads();
        #pragma unroll
        for (int a = 0; a < 8; ++a) {
            int i = i0 + a;
            if (i >= NATOMS) break;
            const float4* A4 = (const float4*)Arow[a];
            float s = 0.f;
            #pragma unroll
            for (int kk = 0; kk < 16; ++kk) {
                float4 v = A4[kk];
                s += v.x*w[4*kk] + v.y*w[4*kk+1] + v.z*w[4*kk+2] + v.w*w[4*kk+3];
            }
            Pout[i*C2F + c] = s;
        }
    }
}

// ---------------- kernel 2: BN1 batch statistics ----------------
// 1 channel per thread: f = tid&127, sub = tid>>7 (2 atoms per iter).
__global__ __launch_bounds__(256, 6) void k_bn1_stats(
    const int*   __restrict__ nbr,  const float* __restrict__ bond,
    const float* __restrict__ W,    const float* __restrict__ bvec,
    const float* __restrict__ Pself,const float* __restrict__ Pnbr,
    float* __restrict__ partial1)
{
    __shared__ float BondL[2][MNBR][44]; // padded: rows 16B-aligned
    __shared__ int   Ni[2][MNBR];
    __shared__ float red[256];
    const int tid = threadIdx.x;
    const int f   = tid & 127;
    const int sub = tid >> 7;
    float w[BDIM];
    #pragma unroll
    for (int k = 0; k < BDIM; ++k)
        w[k] = W[(C2F + k)*C2F + f];
    const float bb = bvec[f];
    float s = 0.f, q = 0.f;

    for (int i0 = blockIdx.x*2; i0 < NATOMS; i0 += gridDim.x*2) {
        __syncthreads();
        for (int idx = tid; idx < 2*BONDROW; idx += 256) {
            int a = idx / BONDROW, rr = idx - a*BONDROW;
            BondL[a][rr/BDIM][rr%BDIM] = bond[(i0+a)*BONDROW + rr];
        }
        if (tid < 2*MNBR) {
            int a = tid / MNBR, j = tid - a*MNBR;
            Ni[a][j] = nbr[(i0+a)*MNBR + j];
        }
        __syncthreads();
        const int i = i0 + sub;                 // always < NATOMS (N even)
        const float pf = Pself[i*C2F + f] + bb;
        #pragma unroll
        for (int j = 0; j < MNBR; ++j) {
            const int r = Ni[sub][j];
            float g = pf + Pnbr[r*C2F + f];
            const float* brow = BondL[sub][j];  // broadcast reads (same addr)
            #pragma unroll
            for (int kk = 0; kk < 10; ++kk) {
                float4 v = *(const float4*)(brow + 4*kk);
                g += v.x*w[4*kk] + v.y*w[4*kk+1] + v.z*w[4*kk+2] + v.w*w[4*kk+3];
            }
            g += brow[40]*w[40];
            s += g; q += g*g;
        }
    }
    float* pb = partial1 + blockIdx.x*256;      // {sum[128], sumsq[128]}
    red[tid] = s; __syncthreads();
    if (tid < 128) pb[tid] = red[tid] + red[tid+128];
    __syncthreads();
    red[tid] = q; __syncthreads();
    if (tid < 128) pb[128 + tid] = red[tid] + red[tid+128];
}

// ---------------- kernel 3: finalize BN1 params ----------------
__global__ __launch_bounds__(1024) void k_bn1_finalize(
    const float* __restrict__ partial1, const float* __restrict__ scale,
    const float* __restrict__ offset,   float* __restrict__ prm1)
{
    __shared__ float redS[1024], redQ[1024];
    const int tid = threadIdx.x;
    const int c = tid & 127, h = tid >> 7;       // 8 slices
    float S = 0.f, Q = 0.f;
    for (int blk = h; blk < NBLK; blk += 8) {
        S += partial1[blk*256 + c];
        Q += partial1[blk*256 + 128 + c];
    }
    redS[tid] = S; redQ[tid] = Q;
    __syncthreads();
    if (tid < 128) {
        float Sa = 0.f, Qa = 0.f;
        #pragma unroll
        for (int hh = 0; hh < 8; ++hh) { Sa += redS[hh*128 + c]; Qa += redQ[hh*128 + c]; }
        const float invn = 1.f / (float)(NATOMS * MNBR);
        float mean = Sa * invn;
        float var  = Qa * invn - mean*mean;
        float inv  = scale[c] * rsqrtf(var + EPSBN);
        prm1[c]       = inv;
        prm1[128 + c] = offset[c] - mean*inv;    // folded offset
    }
}

// ---------------- kernel 4: main pass ----------------
// Needs channel pair (f, f+64): f = tid&63, slot = tid>>6 (4 atoms/iter).
__global__ __launch_bounds__(256, 4) void k_main(
    const int*   __restrict__ nbr,  const float* __restrict__ bond,
    const float* __restrict__ W,    const float* __restrict__ bvec,
    const float* __restrict__ Pself,const float* __restrict__ Pnbr,
    const float* __restrict__ prm1,
    float* __restrict__ summed, float* __restrict__ partial2)
{
    __shared__ float BondL[4][MNBR][44];
    __shared__ int   Ni[4][MNBR];
    __shared__ float red[256];
    const int tid  = threadIdx.x;
    const int f    = tid & 63;
    const int slot = tid >> 6;
    float wf[BDIM], wc[BDIM];
    #pragma unroll
    for (int k = 0; k < BDIM; ++k) {
        wf[k] = W[(C2F + k)*C2F + f];
        wc[k] = W[(C2F + k)*C2F + f + 64];
    }
    const float bb0 = bvec[f], bb1 = bvec[f + 64];
    const float iv0 = prm1[f],      of0 = prm1[128 + f];
    const float iv1 = prm1[f + 64], of1 = prm1[192 + f];
    float s2 = 0.f, q2 = 0.f;

    for (int i0 = blockIdx.x*4; i0 < NATOMS; i0 += gridDim.x*4) {
        __syncthreads();
        for (int idx = tid; idx < 4*BONDROW; idx += 256) {
            int a = idx / BONDROW, rr = idx - a*BONDROW;
            BondL[a][rr/BDIM][rr%BDIM] = bond[(i0+a)*BONDROW + rr];
        }
        if (tid < 4*MNBR) {
            int a = tid / MNBR, j = tid - a*MNBR;
            Ni[a][j] = nbr[(i0+a)*MNBR + j];
        }
        __syncthreads();
        const int i = i0 + slot;                 // always < NATOMS (N % 4 == 0)
        const float pf0 = Pself[i*C2F + f]      + bb0;
        const float pf1 = Pself[i*C2F + f + 64] + bb1;
        float acc = 0.f;
        #pragma unroll 4
        for (int j = 0; j < MNBR; ++j) {
            const int r = Ni[slot][j];
            float g0 = pf0 + Pnbr[r*C2F + f];
            float g1 = pf1 + Pnbr[r*C2F + f + 64];
            const float* brow = BondL[slot][j];
            #pragma unroll
            for (int kk = 0; kk < 10; ++kk) {
                float4 v = *(const float4*)(brow + 4*kk);
                g0 += v.x*wf[4*kk] + v.y*wf[4*kk+1] + v.z*wf[4*kk+2] + v.w*wf[4*kk+3];
                g1 += v.x*wc[4*kk] + v.y*wc[4*kk+1] + v.z*wc[4*kk+2] + v.w*wc[4*kk+3];
            }
            const float bl = brow[40];
            g0 += bl*wf[40]; g1 += bl*wc[40];
            float y0 = g0*iv0 + of0;             // filter channel (BN1 folded)
            float y1 = g1*iv1 + of1;             // core channel
            acc += sigmoidf(y0) * softplusf(y1);
        }
        summed[i*FDIM + f] = acc;
        s2 += acc; q2 += acc*acc;
    }
    float* pb = partial2 + blockIdx.x*128;       // {sum[64], sumsq[64]}
    red[tid] = s2; __syncthreads();
    if (tid < 64) pb[tid]      = red[tid] + red[tid+64] + red[tid+128] + red[tid+192];
    __syncthreads();
    red[tid] = q2; __syncthreads();
    if (tid < 64) pb[64 + tid] = red[tid] + red[tid+64] + red[tid+128] + red[tid+192];
}

// ---------------- kernel 5: finalize BN2 params ----------------
__global__ __launch_bounds__(1024) void k_bn2_finalize(
    const float* __restrict__ partial2, const float* __restrict__ scale,
    const float* __restrict__ offset,   float* __restrict__ prm2)
{
    __shared__ float redS[1024], redQ[1024];
    const int tid = threadIdx.x;
    const int f = tid & 63, h = tid >> 6;        // 16 slices
    float S = 0.f, Q = 0.f;
    for (int blk = h; blk < NBLK; blk += 16) {
        S += partial2[blk*128 + f];
        Q += partial2[blk*128 + 64 + f];
    }
    redS[tid] = S; redQ[tid] = Q;
    __syncthreads();
    if (tid < 64) {
        float Sa = 0.f, Qa = 0.f;
        #pragma unroll
        for (int hh = 0; hh < 16; ++hh) { Sa += redS[hh*64 + f]; Qa += redQ[hh*64 + f]; }
        const float invn = 1.f / (float)NATOMS;
        float mean = Sa * invn;
        float var  = Qa * invn - mean*mean;
        float inv  = scale[f] * rsqrtf(var + EPSBN);
        prm2[f]      = inv;
        prm2[64 + f] = offset[f] - mean*inv;
    }
}

// ---------------- kernel 6: residual + softplus ----------------
__global__ __launch_bounds__(256) void k_final(
    const float* __restrict__ atom, const float* __restrict__ summed,
    const float* __restrict__ prm2, float* __restrict__ out)
{
    __shared__ float iv[64], of[64];
    if (threadIdx.x < 64) {
        iv[threadIdx.x] = prm2[threadIdx.x];
        of[threadIdx.x] = prm2[64 + threadIdx.x];
    }
    __syncthreads();
    const int total4 = NATOMS*FDIM/4;
    for (int t = blockIdx.x*blockDim.x + threadIdx.x; t < total4;
         t += gridDim.x*blockDim.x) {
        float4 a = ((const float4*)atom)[t];
        float4 s = ((const float4*)summed)[t];
        int fb = (t*4) & 63;
        float4 r;
        r.x = softplusf(a.x + s.x*iv[fb]   + of[fb]);
        r.y = softplusf(a.y + s.y*iv[fb+1] + of[fb+1]);
        r.z = softplusf(a.z + s.z*iv[fb+2] + of[fb+2]);
        r.w = softplusf(a.w + s.w*iv[fb+3] + of[fb+3]);
        ((float4*)out)[t] = r;
    }
}

extern "C" void kernel_launch(void* const* d_in, const int* in_sizes, int n_in,
                              void* d_out, int out_size, void* d_ws, size_t ws_size,
                              hipStream_t stream)
{
    const int*   nbr  = (const int*)  d_in[0];
    const float* atom = (const float*)d_in[1];
    const float* bond = (const float*)d_in[2];
    const float* W    = (const float*)d_in[3];
    const float* bvec = (const float*)d_in[4];
    const float* s1   = (const float*)d_in[5];
    const float* o1   = (const float*)d_in[6];
    const float* s2   = (const float*)d_in[7];
    const float* o2   = (const float*)d_in[8];
    float* out = (float*)d_out;

    float* ws       = (float*)d_ws;
    float* Pself    = ws;                                  // N*128
    float* Pnbr     = Pself    + (size_t)NATOMS*C2F;       // N*128
    float* summed   = Pnbr     + (size_t)NATOMS*C2F;       // N*64
    float* partial1 = summed   + (size_t)NATOMS*FDIM;      // NBLK*256
    float* partial2 = partial1 + (size_t)NBLK*256;         // NBLK*128
    float* prm1     = partial2 + (size_t)NBLK*128;         // 256
    float* prm2     = prm1     + 256;                      // 128

    hipLaunchKernelGGL(k_project,      dim3(512),  dim3(256),  0, stream,
                       atom, W, Pself, Pnbr);
    hipLaunchKernelGGL(k_bn1_stats,    dim3(NBLK), dim3(256),  0, stream,
                       nbr, bond, W, bvec, Pself, Pnbr, partial1);
    hipLaunchKernelGGL(k_bn1_finalize, dim3(1),    dim3(1024), 0, stream,
                       partial1, s1, o1, prm1);
    hipLaunchKernelGGL(k_main,         dim3(NBLK), dim3(256),  0, stream,
                       nbr, bond, W, bvec, Pself, Pnbr, prm1, summed, partial2);
    hipLaunchKernelGGL(k_bn2_finalize, dim3(1),    dim3(1024), 0, stream,
                       partial2, s2, o2, prm2);
    hipLaunchKernelGGL(k_final,        dim3(2048), dim3(256),  0, stream,
                       atom, summed, prm2, out);
}

// Round 3
// 1442.120 us; speedup vs baseline: 4.0660x; 4.0660x over previous
//
#include <hip/hip_runtime.h>
#include <math.h>

// CGConv: N=100000 atoms, M=12 nbrs, F=64 atom-feat, B=41 bond-feat
// gated = [self | nbr | bond] @ W + b ; BN1 over N*M rows ;
// summed = sum_j sigmoid(filter)*softplus(core) ; BN2 over N rows ;
// out = softplus(atom + summed_bn)
//
// R3 design: no LDS staging, no barriers in hot loops.
// - atom index made wave-uniform via readfirstlane -> bond/nbr loads are
//   uniform-address scalar loads (s_load into SGPRs), FMA = v_fmac(s,v).
// - Pnbr stored bf16 (25.6MB, ~fits one XCD L2) -> gather traffic halved.
// - launch_bounds(256,4): 128-VGPR cap. R2 lesson: the (256,6)=85 cap made
//   the allocator spill w[41] to scratch (VGPR=40, 15GB of HBM traffic).

#define NATOMS  100000
#define MNBR    12
#define FDIM    64
#define BDIM    41
#define C2F     128
#define BONDROW (MNBR*BDIM)   // 492
#define EPSBN   1e-5f
#define NBLK    2048          // grid for pair kernels (= #partial slots)

__device__ __forceinline__ float softplusf(float x) {
    return fmaxf(x, 0.f) + log1pf(__expf(-fabsf(x)));
}
__device__ __forceinline__ float sigmoidf(float x) {
    return 1.f / (1.f + __expf(-x));
}
__device__ __forceinline__ float bf2f(unsigned short u) {
    unsigned int v = ((unsigned int)u) << 16;
    return __builtin_bit_cast(float, v);
}
__device__ __forceinline__ unsigned short f2bf(float f) {
    unsigned int x = __builtin_bit_cast(unsigned int, f);
    unsigned int r = (x + 0x7fff + ((x >> 16) & 1)) >> 16;  // RNE
    return (unsigned short)r;
}

// ---------------- kernel 1: per-atom projections ----------------
// Pself[i][c] (f32) = atom[i] @ W_self col c ; Pnbr[i][c] (bf16) = atom[i] @ W_nbr col c
__global__ __launch_bounds__(256) void k_project(
    const float* __restrict__ atom, const float* __restrict__ W,
    float* __restrict__ Pself, unsigned short* __restrict__ PnbrBf)
{
    __shared__ float Arow[8][64];
    const int tid  = threadIdx.x;
    const int c    = tid & 127;
    const int half = tid >> 7;           // 0 -> Pself, 1 -> Pnbr
    float w[64];
    #pragma unroll
    for (int k = 0; k < 64; ++k)
        w[k] = W[(half*64 + k)*C2F + c];

    for (int i0 = blockIdx.x*8; i0 < NATOMS; i0 += gridDim.x*8) {
        __syncthreads();
        for (int idx = tid; idx < 8*64; idx += 256) {
            int a = idx >> 6, k = idx & 63, i = i0 + a;
            Arow[a][k] = (i < NATOMS) ? atom[i*FDIM + k] : 0.f;
        }
        __syncthreads();
        #pragma unroll
        for (int a = 0; a < 8; ++a) {
            int i = i0 + a;
            if (i >= NATOMS) break;
            const float4* A4 = (const float4*)Arow[a];
            float s = 0.f;
            #pragma unroll
            for (int kk = 0; kk < 16; ++kk) {
                float4 v = A4[kk];
                s += v.x*w[4*kk] + v.y*w[4*kk+1] + v.z*w[4*kk+2] + v.w*w[4*kk+3];
            }
            if (half == 0) Pself[(size_t)i*C2F + c] = s;
            else           PnbrBf[(size_t)i*C2F + c] = f2bf(s);
        }
    }
}

// ---------------- kernel 2: BN1 batch statistics ----------------
// 1 channel/thread: f = tid&127; sub (atom slot, 2/block) is wave-uniform.
__global__ __launch_bounds__(256, 4) void k_bn1_stats(
    const int*   __restrict__ nbr,  const float* __restrict__ bond,
    const float* __restrict__ W,    const float* __restrict__ bvec,
    const float* __restrict__ Pself,const unsigned short* __restrict__ Pnbr,
    float* __restrict__ partial1)
{
    __shared__ float red[256];
    const int tid = threadIdx.x;
    const int f   = tid & 127;
    const int sub = __builtin_amdgcn_readfirstlane(tid >> 7);  // wave-uniform
    float w[BDIM];
    #pragma unroll
    for (int k = 0; k < BDIM; ++k)
        w[k] = W[(C2F + k)*C2F + f];
    const float bb = bvec[f];
    float s = 0.f, q = 0.f;

    for (int i = blockIdx.x*2 + sub; i < NATOMS; i += gridDim.x*2) {
        const float pf = Pself[(size_t)i*C2F + f] + bb;
        const float* brow0 = bond + (size_t)i*BONDROW;   // uniform base
        const int*   nrow  = nbr + i*MNBR;               // uniform base
        #pragma unroll
        for (int j = 0; j < MNBR; ++j) {
            const int r = nrow[j];                       // uniform (s_load)
            float ga = pf + bf2f(Pnbr[(size_t)r*C2F + f]);
            float gb = 0.f;
            const float* brow = brow0 + j*BDIM;          // uniform row
            #pragma unroll
            for (int k = 0; k < 20; ++k) ga += brow[k]*w[k];
            #pragma unroll
            for (int k = 20; k < BDIM; ++k) gb += brow[k]*w[k];
            float g = ga + gb;
            s += g; q += g*g;
        }
    }
    float* pb = partial1 + blockIdx.x*256;               // {sum[128], sumsq[128]}
    red[tid] = s; __syncthreads();
    if (tid < 128) pb[tid] = red[tid] + red[tid+128];
    __syncthreads();
    red[tid] = q; __syncthreads();
    if (tid < 128) pb[128 + tid] = red[tid] + red[tid+128];
}

// ---------------- kernel 3: finalize BN1 params ----------------
__global__ __launch_bounds__(1024) void k_bn1_finalize(
    const float* __restrict__ partial1, const float* __restrict__ scale,
    const float* __restrict__ offset,   float* __restrict__ prm1)
{
    __shared__ float redS[1024], redQ[1024];
    const int tid = threadIdx.x;
    const int c = tid & 127, h = tid >> 7;               // 8 slices
    float S = 0.f, Q = 0.f;
    for (int blk = h; blk < NBLK; blk += 8) {
        S += partial1[blk*256 + c];
        Q += partial1[blk*256 + 128 + c];
    }
    redS[tid] = S; redQ[tid] = Q;
    __syncthreads();
    if (tid < 128) {
        float Sa = 0.f, Qa = 0.f;
        #pragma unroll
        for (int hh = 0; hh < 8; ++hh) { Sa += redS[hh*128 + c]; Qa += redQ[hh*128 + c]; }
        const float invn = 1.f / (float)(NATOMS * MNBR);
        float mean = Sa * invn;
        float var  = Qa * invn - mean*mean;
        float inv  = scale[c] * rsqrtf(var + EPSBN);
        prm1[c]       = inv;
        prm1[128 + c] = offset[c] - mean*inv;            // folded offset
    }
}

// ---------------- kernel 4: main pass ----------------
// Channel pair (f, f+64) per thread; slot (atom, 4/block) wave-uniform.
__global__ __launch_bounds__(256, 4) void k_main(
    const int*   __restrict__ nbr,  const float* __restrict__ bond,
    const float* __restrict__ W,    const float* __restrict__ bvec,
    const float* __restrict__ Pself,const unsigned short* __restrict__ Pnbr,
    const float* __restrict__ prm1,
    float* __restrict__ summed, float* __restrict__ partial2)
{
    __shared__ float red[256];
    const int tid  = threadIdx.x;
    const int f    = tid & 63;
    const int slot = __builtin_amdgcn_readfirstlane(tid >> 6); // wave-uniform
    float wf[BDIM], wc[BDIM];
    #pragma unroll
    for (int k = 0; k < BDIM; ++k) {
        wf[k] = W[(C2F + k)*C2F + f];
        wc[k] = W[(C2F + k)*C2F + f + 64];
    }
    const float bb0 = bvec[f], bb1 = bvec[f + 64];
    const float iv0 = prm1[f],      of0 = prm1[128 + f];
    const float iv1 = prm1[f + 64], of1 = prm1[192 + f];
    float s2 = 0.f, q2 = 0.f;

    for (int i = blockIdx.x*4 + slot; i < NATOMS; i += gridDim.x*4) {
        const float pf0 = Pself[(size_t)i*C2F + f]      + bb0;
        const float pf1 = Pself[(size_t)i*C2F + f + 64] + bb1;
        const float* brow0 = bond + (size_t)i*BONDROW;   // uniform base
        const int*   nrow  = nbr + i*MNBR;               // uniform base
        float acc = 0.f;
        #pragma unroll 4
        for (int j = 0; j < MNBR; ++j) {
            const int r = nrow[j];                       // uniform (s_load)
            float g0 = pf0 + bf2f(Pnbr[(size_t)r*C2F + f]);
            float g1 = pf1 + bf2f(Pnbr[(size_t)r*C2F + f + 64]);
            const float* brow = brow0 + j*BDIM;          // uniform row
            #pragma unroll
            for (int k = 0; k < BDIM; ++k) {
                g0 += brow[k]*wf[k];
                g1 += brow[k]*wc[k];
            }
            float y0 = g0*iv0 + of0;                     // BN1 filter (folded)
            float y1 = g1*iv1 + of1;                     // BN1 core
            acc += sigmoidf(y0) * softplusf(y1);
        }
        summed[(size_t)i*FDIM + f] = acc;
        s2 += acc; q2 += acc*acc;
    }
    float* pb = partial2 + blockIdx.x*128;               // {sum[64], sumsq[64]}
    red[tid] = s2; __syncthreads();
    if (tid < 64) pb[tid]      = red[tid] + red[tid+64] + red[tid+128] + red[tid+192];
    __syncthreads();
    red[tid] = q2; __syncthreads();
    if (tid < 64) pb[64 + tid] = red[tid] + red[tid+64] + red[tid+128] + red[tid+192];
}

// ---------------- kernel 5: finalize BN2 params ----------------
__global__ __launch_bounds__(1024) void k_bn2_finalize(
    const float* __restrict__ partial2, const float* __restrict__ scale,
    const float* __restrict__ offset,   float* __restrict__ prm2)
{
    __shared__ float redS[1024], redQ[1024];
    const int tid = threadIdx.x;
    const int f = tid & 63, h = tid >> 6;                // 16 slices
    float S = 0.f, Q = 0.f;
    for (int blk = h; blk < NBLK; blk += 16) {
        S += partial2[blk*128 + f];
        Q += partial2[blk*128 + 64 + f];
    }
    redS[tid] = S; redQ[tid] = Q;
    __syncthreads();
    if (tid < 64) {
        float Sa = 0.f, Qa = 0.f;
        #pragma unroll
        for (int hh = 0; hh < 16; ++hh) { Sa += redS[hh*64 + f]; Qa += redQ[hh*64 + f]; }
        const float invn = 1.f / (float)NATOMS;
        float mean = Sa * invn;
        float var  = Qa * invn - mean*mean;
        float inv  = scale[f] * rsqrtf(var + EPSBN);
        prm2[f]      = inv;
        prm2[64 + f] = offset[f] - mean*inv;
    }
}

// ---------------- kernel 6: residual + softplus ----------------
__global__ __launch_bounds__(256) void k_final(
    const float* __restrict__ atom, const float* __restrict__ summed,
    const float* __restrict__ prm2, float* __restrict__ out)
{
    __shared__ float iv[64], of[64];
    if (threadIdx.x < 64) {
        iv[threadIdx.x] = prm2[threadIdx.x];
        of[threadIdx.x] = prm2[64 + threadIdx.x];
    }
    __syncthreads();
    const int total4 = NATOMS*FDIM/4;
    for (int t = blockIdx.x*blockDim.x + threadIdx.x; t < total4;
         t += gridDim.x*blockDim.x) {
        float4 a = ((const float4*)atom)[t];
        float4 s = ((const float4*)summed)[t];
        int fb = (t*4) & 63;
        float4 r;
        r.x = softplusf(a.x + s.x*iv[fb]   + of[fb]);
        r.y = softplusf(a.y + s.y*iv[fb+1] + of[fb+1]);
        r.z = softplusf(a.z + s.z*iv[fb+2] + of[fb+2]);
        r.w = softplusf(a.w + s.w*iv[fb+3] + of[fb+3]);
        ((float4*)out)[t] = r;
    }
}

extern "C" void kernel_launch(void* const* d_in, const int* in_sizes, int n_in,
                              void* d_out, int out_size, void* d_ws, size_t ws_size,
                              hipStream_t stream)
{
    const int*   nbr  = (const int*)  d_in[0];
    const float* atom = (const float*)d_in[1];
    const float* bond = (const float*)d_in[2];
    const float* W    = (const float*)d_in[3];
    const float* bvec = (const float*)d_in[4];
    const float* s1   = (const float*)d_in[5];
    const float* o1   = (const float*)d_in[6];
    const float* s2   = (const float*)d_in[7];
    const float* o2   = (const float*)d_in[8];
    float* out = (float*)d_out;

    float*          Pself  = (float*)d_ws;                              // N*128 f32
    unsigned short* PnbrBf = (unsigned short*)(Pself + (size_t)NATOMS*C2F); // N*128 bf16
    float*          summed = (float*)(PnbrBf + (size_t)NATOMS*C2F);     // N*64 f32
    float* partial1 = summed   + (size_t)NATOMS*FDIM;                   // NBLK*256
    float* partial2 = partial1 + (size_t)NBLK*256;                      // NBLK*128
    float* prm1     = partial2 + (size_t)NBLK*128;                      // 256
    float* prm2     = prm1     + 256;                                   // 128

    hipLaunchKernelGGL(k_project,      dim3(1024), dim3(256),  0, stream,
                       atom, W, Pself, PnbrBf);
    hipLaunchKernelGGL(k_bn1_stats,    dim3(NBLK), dim3(256),  0, stream,
                       nbr, bond, W, bvec, Pself, PnbrBf, partial1);
    hipLaunchKernelGGL(k_bn1_finalize, dim3(1),    dim3(1024), 0, stream,
                       partial1, s1, o1, prm1);
    hipLaunchKernelGGL(k_main,         dim3(NBLK), dim3(256),  0, stream,
                       nbr, bond, W, bvec, Pself, PnbrBf, prm1, summed, partial2);
    hipLaunchKernelGGL(k_bn2_finalize, dim3(1),    dim3(1024), 0, stream,
                       partial2, s2, o2, prm2);
    hipLaunchKernelGGL(k_final,        dim3(2048), dim3(256),  0, stream,
                       atom, summed, prm2, out);
}